// Round 15
// baseline (485.491 us; speedup 1.0000x reference)
//
#include <hip/hip_runtime.h>
#include <hip/hip_bf16.h>
#include <hip/hip_cooperative_groups.h>
#include <cstdint>

namespace cg = cooperative_groups;

// Problem constants
#define B_ 4
#define S_ 4096
#define D_ 1024
#define DFF_ 4096
#define KSEL_ 2048
#define M_ (B_ * KSEL_)      // 8192 selected rows total
#define NTOK_ (B_ * S_)      // 16384

typedef short bf16x8 __attribute__((ext_vector_type(8)));
typedef float f32x4 __attribute__((ext_vector_type(4)));

__device__ inline unsigned short f2bf(float f) {
    union { float f; unsigned int u; } c; c.f = f;
    unsigned int u = c.u;
    unsigned int r = u + 0x7fffu + ((u >> 16) & 1u);
    return (unsigned short)(r >> 16);
}

// ---------------------------------------------------------------------------
// Fused preprocessing (ONE cooperative dispatch, 256 blocks x 1024 threads):
//   A: router (4096 waves x 4 rows: logits, xb=bf16(x), out=x) + zero rank
//   -- grid.sync --
//   B: rank split-j (512 virtual 256-thread blocks; 2 per block, atomicAdd)
//   -- grid.sync --
//   C: compact on blocks 0-3 (1024-thr rewrite, same ascending-index
//      semantics)  CONCURRENT WITH  W1/W2 transpose+bf16 on blocks 4-255
//      (4 tiles/block/iter, uniform 9-iteration trip count)
//   -- grid.sync --
//   D: loss partials on blocks 0-15; grid.sync; block 0 wave 0 reduces.
// Replaces 8 dispatches (memset, transpose x2-or-1, router, rank, compact,
// loss, loss_final) with 1: removes serial launch gaps and overlaps the
// 4-block compact with the 8192-tile transpose work.
// ---------------------------------------------------------------------------
__global__ __launch_bounds__(1024)
void fused_pre(const float* __restrict__ x, const float* __restrict__ Wr,
               const float* __restrict__ W1, const float* __restrict__ W2,
               float* __restrict__ logits, int* __restrict__ rank,
               int* __restrict__ flags, int* __restrict__ rowidx,
               float* __restrict__ rw, unsigned short* __restrict__ xb,
               float* __restrict__ out, unsigned short* __restrict__ W1bT,
               unsigned short* __restrict__ W2bT, float* __restrict__ partials,
               float* __restrict__ lossout) {
    cg::grid_group grid = cg::this_grid();
    const int tid = threadIdx.x;

    __shared__ float sh_lg[S_];          // compact: 16 KB
    __shared__ int   sh_f[S_];           // compact: 16 KB
    __shared__ int   sh_tsum[1024];      // compact prefix: 4 KB
    __shared__ float sh_red[1024];       // reductions: 4 KB
    __shared__ float sh_tile[4][32][33]; // transpose: 16.9 KB
    __shared__ float sh_lj[2][512];      // rank: 4 KB

    // ---------------- Phase A: router + zero rank ----------------
    {
        int zi = blockIdx.x * 1024 + tid;
        if (zi < NTOK_) rank[zi] = 0;

        int gw = blockIdx.x * 16 + (tid >> 6);   // 4096 waves
        int lane = tid & 63;
        for (int row = gw; row < NTOK_; row += 4096) {
            const float* xr = x + (size_t)row * D_;
            unsigned short* xbr = xb + (size_t)row * D_;
            float* outr = out + (size_t)row * D_;
            float acc = 0.f;
#pragma unroll
            for (int j = 0; j < 4; j++) {
                int off = j * 256 + lane * 4;
                float4 v = *(const float4*)(xr + off);
                float4 wv = *(const float4*)(Wr + off);
                acc += v.x * wv.x + v.y * wv.y + v.z * wv.z + v.w * wv.w;
                *(float4*)(outr + off) = v;
                ushort4 o;
                o.x = f2bf(v.x); o.y = f2bf(v.y); o.z = f2bf(v.z); o.w = f2bf(v.w);
                *(ushort4*)(xbr + off) = o;
            }
#pragma unroll
            for (int s = 32; s; s >>= 1) acc += __shfl_xor(acc, s);
            if (lane == 0) logits[row] = acc;
        }
    }
    grid.sync();

    // ---------------- Phase B: rank (512 virtual blocks, 2/block) --------
    {
        int g = tid >> 8;          // 0..3 (groups of 256)
        int lt = tid & 255;
        int b = 0, ic = 0, jc = 0;
        if (g < 2) {
            int vb = blockIdx.x * 2 + g;
            b = vb >> 7; ic = (vb >> 3) & 15; jc = vb & 7;
            const float* L = logits + b * S_;
            for (int t = lt; t < 512; t += 256) sh_lj[g][t] = L[jc * 512 + t];
        }
        __syncthreads();
        if (g < 2) {
            const float* L = logits + b * S_;
            int i = ic * 256 + lt;
            float li = L[i];
            int jbase = jc * 512;
            int r = 0;
            const float4* lj4 = (const float4*)sh_lj[g];
#pragma unroll 4
            for (int q = 0; q < 128; q++) {
                float4 v = lj4[q];
                int jb = jbase + q * 4;
                r += (v.x > li) | ((v.x == li) & (jb     < i));
                r += (v.y > li) | ((v.y == li) & (jb + 1 < i));
                r += (v.z > li) | ((v.z == li) & (jb + 2 < i));
                r += (v.w > li) | ((v.w == li) & (jb + 3 < i));
            }
            atomicAdd(&rank[b * S_ + i], r);
        }
    }
    grid.sync();

    // ---------------- Phase C: compact (blocks 0-3) || transpose ---------
    if (blockIdx.x < 4) {
        int b = blockIdx.x;
        const float* L = logits + b * S_;
        const int* R = rank + b * S_;
        int* F = flags + b * S_;
        // load (S_/4 = 1024 float4s, one per thread)
        {
            ((float4*)sh_lg)[tid] = ((const float4*)L)[tid];
            int4 rk = ((const int4*)R)[tid];
            int4 fl;
            fl.x = rk.x < KSEL_; fl.y = rk.y < KSEL_;
            fl.z = rk.z < KSEL_; fl.w = rk.w < KSEL_;
            ((int4*)sh_f)[tid] = fl;
            ((int4*)F)[tid] = fl;
        }
        __syncthreads();
        // max over this thread's 4 elements, then tree
        float mx = fmaxf(fmaxf(sh_lg[tid * 4], sh_lg[tid * 4 + 1]),
                         fmaxf(sh_lg[tid * 4 + 2], sh_lg[tid * 4 + 3]));
        sh_red[tid] = mx; __syncthreads();
        for (int s = 512; s; s >>= 1) {
            if (tid < s) sh_red[tid] = fmaxf(sh_red[tid], sh_red[tid + s]);
            __syncthreads();
        }
        float m = sh_red[0];
        __syncthreads();
        // esum + selected count over own 4 elements
        float esum = 0.f;
        int s0 = 0;
#pragma unroll
        for (int j = 0; j < 4; j++) {
            int i = tid * 4 + j;
            s0 += sh_f[i];
            if (sh_f[i]) esum += expf(sh_lg[i] - m);
        }
        sh_red[tid] = esum; __syncthreads();
        for (int s = 512; s; s >>= 1) {
            if (tid < s) sh_red[tid] += sh_red[tid + s];
            __syncthreads();
        }
        float inv = 1.f / sh_red[0];
        // exclusive prefix over per-thread counts
        sh_tsum[tid] = s0; __syncthreads();
        for (int s = 1; s < 1024; s <<= 1) {
            int u = (tid >= s) ? sh_tsum[tid - s] : 0;
            __syncthreads();
            sh_tsum[tid] += u;
            __syncthreads();
        }
        int pos = sh_tsum[tid] - s0;
#pragma unroll
        for (int j = 0; j < 4; j++) {
            int i = tid * 4 + j;
            if (sh_f[i]) {
                rowidx[b * KSEL_ + pos] = b * S_ + i;
                rw[b * KSEL_ + pos] = expf(sh_lg[i] - m) * inv;
                pos++;
            }
        }
    } else {
        // transposes: 8192 tiles over 252 blocks x 4 groups, 9 uniform iters
        int group = tid >> 8;
        int tx = tid & 31, ty = (tid >> 5) & 7;
        const int TILES = 2 * (DFF_ / 32) * (D_ / 32);   // 8192
        for (int it = 0; it < 9; ++it) {
            int tile = (blockIdx.x - 4) * 4 + group + it * 1008;
            bool ok = tile < TILES;
            const float* src = nullptr; unsigned short* dst = nullptr;
            int R = 0, C = 0, bx = 0, by = 0;
            if (ok) {
                if (tile < (DFF_ / 32) * (D_ / 32)) {
                    src = W1; dst = W1bT; R = D_; C = DFF_;
                    bx = tile % (DFF_ / 32); by = tile / (DFF_ / 32);
                } else {
                    int t2 = tile - (DFF_ / 32) * (D_ / 32);
                    src = W2; dst = W2bT; R = DFF_; C = D_;
                    bx = t2 % (D_ / 32); by = t2 / (D_ / 32);
                }
                int c0 = bx * 32, r0 = by * 32;
                for (int i = ty; i < 32; i += 8)
                    sh_tile[group][i][tx] = src[(size_t)(r0 + i) * C + c0 + tx];
            }
            __syncthreads();
            if (ok) {
                int c0 = bx * 32, r0 = by * 32;
                for (int i = ty; i < 32; i += 8)
                    dst[(size_t)(c0 + i) * R + r0 + tx] = f2bf(sh_tile[group][tx][i]);
            }
            __syncthreads();
        }
    }
    grid.sync();

    // ---------------- Phase D: loss ----------------
    if (blockIdx.x < 16) {
        int i = blockIdx.x * 1024 + tid;
        float l = logits[i];
        float t = 0.f;
        if (i < S_)
            t = (flags[i] | flags[S_ + i] | flags[2 * S_ + i] | flags[3 * S_ + i]) ? 1.f : 0.f;
        float v = fmaxf(l, 0.f) - l * t + log1pf(expf(-fabsf(l)));
        sh_red[tid] = v; __syncthreads();
        for (int s = 512; s; s >>= 1) {
            if (tid < s) sh_red[tid] += sh_red[tid + s];
            __syncthreads();
        }
        if (tid == 0) partials[blockIdx.x] = sh_red[0];
    }
    grid.sync();
    if (blockIdx.x == 0 && tid < 64) {
        float v = (tid < 16) ? partials[tid] : 0.f;
#pragma unroll
        for (int s = 32; s; s >>= 1) v += __shfl_xor(v, s);
        if (tid == 0) lossout[0] = v / (float)NTOK_;
    }
}

// ---------------------------------------------------------------------------
// GEMM (round-7 measured best): fine-phased 128x256 pipeline, 3-slot ring,
// counted vmcnt(6), persistent SUBS M-tiles/block.
// MODE 1: H = silu(gather(A) @ W1), bf16 (SUBS=4, grid 256 = 1/CU).
// MODE 2: out[rowidx[m]] = x[rowidx[m]] + (H@W2)[m]*rw[m] (SUBS=1).
// ---------------------------------------------------------------------------
template <int MODE, int N, int K, int SUBS>
__global__ __launch_bounds__(512, 2)
void gemm_pipe_kernel(const unsigned short* __restrict__ A,
                      const unsigned short* __restrict__ BT,
                      const int* __restrict__ rowidx,
                      const float* __restrict__ rw,
                      const float* __restrict__ x,
                      unsigned short* __restrict__ Hout,
                      float* __restrict__ Out) {
    constexpr int BM = 128, BN = 256, BK = 64;
    constexpr int KI = K / BK;
    constexpr int NT = N / BN;
    constexpr int MG = M_ / (BM * SUBS);
    constexpr int NWG = NT * MG;
    constexpr int CPX = NWG / 8;
    __shared__ __attribute__((aligned(16))) unsigned short As[3][BM * BK];
    __shared__ __attribute__((aligned(16))) unsigned short Bs[3][BN * BK];

    const int tid = threadIdx.x;
    const int w = tid >> 6, lane = tid & 63;
    const int wm = w >> 2, wn = w & 3;

    int wgid = blockIdx.y * NT + blockIdx.x;
    int swz = (wgid & 7) * CPX + (wgid >> 3);
    const int tile_n = (swz % NT) * BN;
    const int mgrp   = (swz / NT);

    const int srow = lane >> 3;
    const int sw = (lane & 7) ^ srow;
    const uint64_t abase = (uint64_t)(uintptr_t)A;
    const uint64_t bbase = (uint64_t)(uintptr_t)BT;
    uint64_t aaddr[SUBS][2], baddr[4];
#pragma unroll
    for (int s = 0; s < SUBS; ++s)
#pragma unroll
        for (int t = 0; t < 2; ++t) {
            int r = t * 64 + w * 8 + srow;
            int am = (mgrp * SUBS + s) * BM + r;
            int ar = (MODE == 1) ? rowidx[am] : am;
            aaddr[s][t] = abase + ((uint64_t)ar * K + (uint64_t)sw * 8) * 2ull;
        }
#pragma unroll
    for (int t = 0; t < 4; ++t) {
        int r = t * 64 + w * 8 + srow;
        baddr[t] = bbase + ((uint64_t)(tile_n + r) * K + (uint64_t)sw * 8) * 2ull;
    }

    auto gload = [&](unsigned short* lds, uint64_t gaddr) {
        __builtin_amdgcn_global_load_lds(
            (const __attribute__((address_space(1))) unsigned int*)(uintptr_t)gaddr,
            (__attribute__((address_space(3))) unsigned int*)lds, 16, 0, 0);
    };

    f32x4 acc[4][4];
#pragma unroll
    for (int i = 0; i < 4; i++)
#pragma unroll
        for (int j = 0; j < 4; j++) acc[i][j] = (f32x4){0.f, 0.f, 0.f, 0.f};

#pragma unroll
    for (int p = 0; p < 2; ++p) {
        const uint64_t koff = (uint64_t)p * (BK * 2);
        gload(&As[p][(0 * 64 + w * 8) * BK], aaddr[0][0] + koff);
        gload(&As[p][(1 * 64 + w * 8) * BK], aaddr[0][1] + koff);
#pragma unroll
        for (int t = 0; t < 4; ++t)
            gload(&Bs[p][(t * 64 + w * 8) * BK], baddr[t] + koff);
    }
    asm volatile("s_waitcnt vmcnt(6)" ::: "memory");
    asm volatile("s_barrier" ::: "memory");

    const int lr = lane & 15, quad = lane >> 4;
    int c = 0;
#pragma unroll
    for (int s = 0; s < SUBS; ++s) {
#pragma unroll 1
        for (int kt = 0; kt < KI; ++kt) {
            int pre = c + 2; if (pre >= 3) pre -= 3;
            const char* Abase_l = (const char*)&As[c][0];
            const char* Bbase_l = (const char*)&Bs[c][0];
            const bool cross = (kt + 2 >= KI);
            const bool do_stage = (s < SUBS - 1) || (kt + 2 < KI);
            const uint64_t sa0 = cross ? aaddr[(s + 1 < SUBS) ? s + 1 : s][0]
                                       : aaddr[s][0];
            const uint64_t sa1 = cross ? aaddr[(s + 1 < SUBS) ? s + 1 : s][1]
                                       : aaddr[s][1];
            const uint64_t koff = (uint64_t)((kt + 2) & (KI - 1)) * (BK * 2);

            // ================= phase 0 : ks = 0 =================
            {
                bf16x8 af[4], bfr[4];
                const int xo = (quad ^ (lr & 7)) * 16;
#pragma unroll
                for (int m4 = 0; m4 < 4; ++m4) {
                    int row = wm * 64 + m4 * 16 + lr;
                    af[m4] = *(const bf16x8*)(Abase_l + row * (BK * 2) + xo);
                }
#pragma unroll
                for (int n4 = 0; n4 < 4; ++n4) {
                    int col = wn * 64 + n4 * 16 + lr;
                    bfr[n4] = *(const bf16x8*)(Bbase_l + col * (BK * 2) + xo);
                }
                if (do_stage) {
                    gload(&As[pre][(0 * 64 + w * 8) * BK], sa0 + koff);
                    gload(&As[pre][(1 * 64 + w * 8) * BK], sa1 + koff);
                    gload(&Bs[pre][(w * 8) * BK], baddr[0] + koff);
                }
                asm volatile("s_barrier" ::: "memory");
                asm volatile("s_waitcnt lgkmcnt(0)" ::: "memory");
                __builtin_amdgcn_sched_barrier(0);
                __builtin_amdgcn_s_setprio(1);
#pragma unroll
                for (int m4 = 0; m4 < 4; ++m4)
#pragma unroll
                    for (int n4 = 0; n4 < 4; ++n4)
                        acc[m4][n4] = __builtin_amdgcn_mfma_f32_16x16x32_bf16(
                            af[m4], bfr[n4], acc[m4][n4], 0, 0, 0);
                __builtin_amdgcn_s_setprio(0);
                asm volatile("s_barrier" ::: "memory");
            }

            // ================= phase 1 : ks = 1 =================
            {
                bf16x8 af[4], bfr[4];
                const int xo = ((4 + quad) ^ (lr & 7)) * 16;
#pragma unroll
                for (int m4 = 0; m4 < 4; ++m4) {
                    int row = wm * 64 + m4 * 16 + lr;
                    af[m4] = *(const bf16x8*)(Abase_l + row * (BK * 2) + xo);
                }
#pragma unroll
                for (int n4 = 0; n4 < 4; ++n4) {
                    int col = wn * 64 + n4 * 16 + lr;
                    bfr[n4] = *(const bf16x8*)(Bbase_l + col * (BK * 2) + xo);
                }
                if (do_stage) {
#pragma unroll
                    for (int t = 1; t < 4; ++t)
                        gload(&Bs[pre][(t * 64 + w * 8) * BK], baddr[t] + koff);
                }
                asm volatile("s_barrier" ::: "memory");
                asm volatile("s_waitcnt lgkmcnt(0)" ::: "memory");
                __builtin_amdgcn_sched_barrier(0);
                __builtin_amdgcn_s_setprio(1);
#pragma unroll
                for (int m4 = 0; m4 < 4; ++m4)
#pragma unroll
                    for (int n4 = 0; n4 < 4; ++n4)
                        acc[m4][n4] = __builtin_amdgcn_mfma_f32_16x16x32_bf16(
                            af[m4], bfr[n4], acc[m4][n4], 0, 0, 0);
                __builtin_amdgcn_s_setprio(0);
                if (do_stage) {
                    asm volatile("s_waitcnt vmcnt(6)" ::: "memory");
                } else if (kt + 2 == KI) {
                    asm volatile("s_waitcnt vmcnt(0)" ::: "memory");
                }
                asm volatile("s_barrier" ::: "memory");
                c += 1; if (c >= 3) c = 0;
            }
        }

        if (MODE == 1) {
            const int tile_m = (mgrp * SUBS + s) * BM;
#pragma unroll
            for (int m4 = 0; m4 < 4; ++m4)
#pragma unroll
                for (int r = 0; r < 4; ++r) {
                    int m = tile_m + wm * 64 + m4 * 16 + quad * 4 + r;
#pragma unroll
                    for (int n4 = 0; n4 < 4; ++n4) {
                        int col = tile_n + wn * 64 + n4 * 16 + lr;
                        float v = acc[m4][n4][r];
                        v = v / (1.f + __expf(-v));
                        Hout[(uint64_t)m * N + col] = f2bf(v);
                    }
                }
            if (s + 1 < SUBS) {
#pragma unroll
                for (int i = 0; i < 4; i++)
#pragma unroll
                    for (int j = 0; j < 4; j++)
                        acc[i][j] = (f32x4){0.f, 0.f, 0.f, 0.f};
            }
        }
    }

    if (MODE == 2) {
        const int tile_m = mgrp * SUBS * BM;
#pragma unroll
        for (int m4 = 0; m4 < 4; ++m4)
#pragma unroll
            for (int r = 0; r < 4; ++r) {
                int m = tile_m + wm * 64 + m4 * 16 + quad * 4 + r;
                int grow = rowidx[m];
                float wgt = rw[m];
                uint64_t rb = (uint64_t)grow * D_;
#pragma unroll
                for (int n4 = 0; n4 < 4; ++n4) {
                    int col = tile_n + wn * 64 + n4 * 16 + lr;
                    Out[rb + col] = x[rb + col] + acc[m4][n4][r] * wgt;
                }
            }
    }
}

// ---------------------------------------------------------------------------
extern "C" void kernel_launch(void* const* d_in, const int* in_sizes, int n_in,
                              void* d_out, int out_size, void* d_ws, size_t ws_size,
                              hipStream_t stream) {
    const float* x  = (const float*)d_in[0];
    // d_in[1] = mask (unused: all-ones in setup, MLP ignores it)
    const float* Wr = (const float*)d_in[2];
    const float* W1 = (const float*)d_in[3];
    const float* W2 = (const float*)d_in[4];
    float* out = (float*)d_out;

    char* ws = (char*)d_ws;
    size_t off = 0;
    auto alloc = [&](size_t bytes) {
        char* p = ws + off;
        off = (off + bytes + 255) & ~(size_t)255;
        return p;
    };
    unsigned short* xb   = (unsigned short*)alloc((size_t)NTOK_ * D_ * 2);  // 33.5 MB
    unsigned short* W1bT = (unsigned short*)alloc((size_t)DFF_ * D_ * 2);   // 8.4 MB
    unsigned short* W2bT = (unsigned short*)alloc((size_t)D_ * DFF_ * 2);   // 8.4 MB
    unsigned short* H    = (unsigned short*)alloc((size_t)M_ * DFF_ * 2);   // 67 MB
    float* logits  = (float*)alloc(NTOK_ * 4);
    int*   rank    = (int*)alloc(NTOK_ * 4);
    int*   flags   = (int*)alloc(NTOK_ * 4);
    int*   rowidx  = (int*)alloc(M_ * 4);
    float* rwp     = (float*)alloc(M_ * 4);
    float* partials = (float*)alloc(16 * 4);
    float* lossp = out + (size_t)NTOK_ * D_;

    // Fused preprocessing: one cooperative dispatch replaces 8.
    void* kargs[] = {
        (void*)&x, (void*)&Wr, (void*)&W1, (void*)&W2,
        (void*)&logits, (void*)&rank, (void*)&flags, (void*)&rowidx,
        (void*)&rwp, (void*)&xb, (void*)&out, (void*)&W1bT, (void*)&W2bT,
        (void*)&partials, (void*)&lossp
    };
    (void)hipLaunchCooperativeKernel((const void*)fused_pre, dim3(256),
                                     dim3(1024), kargs, 0, stream);

    // GEMM1: H[8192][4096] = silu(gather(xb) @ W1)  -- persistent, 4 M-tiles/block
    gemm_pipe_kernel<1, DFF_, D_, 4><<<dim3(DFF_ / 256, M_ / (128 * 4)), 512, 0, stream>>>(
        xb, W1bT, rowidx, nullptr, nullptr, H, nullptr);
    // GEMM2: out[rowidx[m]] = x[rowidx[m]] + (H @ W2)[m] * rw[m]
    gemm_pipe_kernel<2, D_, DFF_, 1><<<dim3(D_ / 256, M_ / 128), 512, 0, stream>>>(
        H, W2bT, rowidx, rwp, x, nullptr, out);
}

// Round 16
// 354.741 us; speedup vs baseline: 1.3686x; 1.3686x over previous
//
#include <hip/hip_runtime.h>
#include <hip/hip_bf16.h>
#include <cstdint>

// Problem constants
#define B_ 4
#define S_ 4096
#define D_ 1024
#define DFF_ 4096
#define KSEL_ 2048
#define M_ (B_ * KSEL_)      // 8192 selected rows total
#define NTOK_ (B_ * S_)      // 16384

typedef short bf16x8 __attribute__((ext_vector_type(8)));
typedef float f32x4 __attribute__((ext_vector_type(4)));

__device__ inline unsigned short f2bf(float f) {
    union { float f; unsigned int u; } c; c.f = f;
    unsigned int u = c.u;
    unsigned int r = u + 0x7fffu + ((u >> 16) & 1u);
    return (unsigned short)(r >> 16);
}

// ---------------------------------------------------------------------------
// pre_kernel: router + W1/W2 transpose in ONE ordinary launch (blockIdx
// partition, disjoint work, no cross-dependency: rank needs only logits,
// GEMM1 needs W1bT - both after this kernel completes).
//   bid 0..4095      : router (4 waves x 1 row: logits, xb=bf16(x), out=x)
//   bid 4096..12287  : 8192 transpose tiles (W1 then W2), 256 thr = 32x8
// Router blocks first: they are on the rank->compact critical path.
// ---------------------------------------------------------------------------
__global__ __launch_bounds__(256)
void pre_kernel(const float* __restrict__ x, const float* __restrict__ Wr,
                float* __restrict__ logits, unsigned short* __restrict__ xb,
                float* __restrict__ out,
                const float* __restrict__ W1, unsigned short* __restrict__ W1bT,
                const float* __restrict__ W2, unsigned short* __restrict__ W2bT) {
    if (blockIdx.x < NTOK_ / 4) {
        // ----- router (identical to round-7 router_kernel) -----
        int wid = threadIdx.x >> 6, lane = threadIdx.x & 63;
        int row = blockIdx.x * 4 + wid;
        const float* xr = x + (size_t)row * D_;
        unsigned short* xbr = xb + (size_t)row * D_;
        float* outr = out + (size_t)row * D_;
        float acc = 0.f;
#pragma unroll
        for (int j = 0; j < 4; j++) {
            int off = j * 256 + lane * 4;
            float4 v = *(const float4*)(xr + off);
            float4 w = *(const float4*)(Wr + off);
            acc += v.x * w.x + v.y * w.y + v.z * w.z + v.w * w.w;
            *(float4*)(outr + off) = v;
            ushort4 o;
            o.x = f2bf(v.x); o.y = f2bf(v.y); o.z = f2bf(v.z); o.w = f2bf(v.w);
            *(ushort4*)(xbr + off) = o;
        }
#pragma unroll
        for (int s = 32; s; s >>= 1) acc += __shfl_xor(acc, s);
        if (lane == 0) logits[row] = acc;
    } else {
        // ----- transpose (identical math to round-7 transpose_bf16) -----
        __shared__ float tile[32][33];
        int id = blockIdx.x - NTOK_ / 4;
        const float* src; unsigned short* dst; int R, C, bx, by;
        if (id < (DFF_ / 32) * (D_ / 32)) {
            src = W1; dst = W1bT; R = D_; C = DFF_;
            bx = id % (DFF_ / 32); by = id / (DFF_ / 32);
        } else {
            id -= (DFF_ / 32) * (D_ / 32);
            src = W2; dst = W2bT; R = DFF_; C = D_;
            bx = id % (D_ / 32); by = id / (D_ / 32);
        }
        int tx = threadIdx.x & 31, ty = threadIdx.x >> 5;   // 32 x 8
        int c0 = bx * 32, r0 = by * 32;
        for (int i = ty; i < 32; i += 8)
            tile[i][tx] = src[(size_t)(r0 + i) * C + c0 + tx];
        __syncthreads();
        for (int i = ty; i < 32; i += 8)
            dst[(size_t)(c0 + i) * R + r0 + tx] = f2bf(tile[tx][i]);
    }
}

// ---------------------------------------------------------------------------
// Rank (split-j): partial rank over a 512-logit j-chunk, atomicAdd into rank[].
// ---------------------------------------------------------------------------
__global__ __launch_bounds__(256)
void rank_partial_kernel(const float* __restrict__ logits, int* __restrict__ rank) {
    __shared__ float lj[512];
    int b  = blockIdx.x >> 7;
    int ic = (blockIdx.x >> 3) & 15;
    int jc = blockIdx.x & 7;
    const float* L = logits + b * S_;
    for (int t = threadIdx.x; t < 512; t += 256) lj[t] = L[jc * 512 + t];
    __syncthreads();
    int i = ic * 256 + threadIdx.x;
    float li = L[i];
    int jbase = jc * 512;
    int r = 0;
    const float4* __restrict__ lj4 = (const float4*)lj;
#pragma unroll 4
    for (int q = 0; q < 128; q++) {
        float4 v = lj4[q];
        int jb = jbase + q * 4;
        r += (v.x > li) | ((v.x == li) & (jb     < i));
        r += (v.y > li) | ((v.y == li) & (jb + 1 < i));
        r += (v.z > li) | ((v.z == li) & (jb + 2 < i));
        r += (v.w > li) | ((v.w == li) & (jb + 3 < i));
    }
    atomicAdd(&rank[b * S_ + i], r);
}

// ---------------------------------------------------------------------------
// Compact: sel = rank < KSEL_; flags, softmax weights, prefix-sum -> rowidx/rw.
// ---------------------------------------------------------------------------
__global__ __launch_bounds__(256)
void compact_kernel(const float* __restrict__ logits, const int* __restrict__ rank,
                    int* __restrict__ flags,
                    int* __restrict__ rowidx, float* __restrict__ rw) {
    __shared__ float lg[S_];
    __shared__ int f[S_];
    __shared__ int tsum[256];
    __shared__ float red[256];
    int b = blockIdx.x;
    const float* L = logits + b * S_;
    const int* R = rank + b * S_;
    int* F = flags + b * S_;
    for (int j = threadIdx.x; j < S_ / 4; j += 256) {
        ((float4*)lg)[j] = ((const float4*)L)[j];
        int4 rk = ((const int4*)R)[j];
        int4 fl;
        fl.x = rk.x < KSEL_; fl.y = rk.y < KSEL_;
        fl.z = rk.z < KSEL_; fl.w = rk.w < KSEL_;
        ((int4*)f)[j] = fl;
        ((int4*)F)[j] = fl;
    }
    __syncthreads();
    float mx = -INFINITY;
    for (int j = threadIdx.x; j < S_; j += 256) mx = fmaxf(mx, lg[j]);
    red[threadIdx.x] = mx; __syncthreads();
    for (int s = 128; s; s >>= 1) {
        if (threadIdx.x < s) red[threadIdx.x] = fmaxf(red[threadIdx.x], red[threadIdx.x + s]);
        __syncthreads();
    }
    float m = red[0];
    __syncthreads();

    float esum = 0.f;
    int s0 = 0;
#pragma unroll
    for (int j = 0; j < 16; j++) {
        int i = threadIdx.x * 16 + j;
        s0 += f[i];
        if (f[i]) esum += expf(lg[i] - m);
    }
    red[threadIdx.x] = esum; __syncthreads();
    for (int s = 128; s; s >>= 1) {
        if (threadIdx.x < s) red[threadIdx.x] += red[threadIdx.x + s];
        __syncthreads();
    }
    float inv = 1.f / red[0];

    tsum[threadIdx.x] = s0; __syncthreads();
    for (int s = 1; s < 256; s <<= 1) {
        int u = (threadIdx.x >= s) ? tsum[threadIdx.x - s] : 0;
        __syncthreads();
        tsum[threadIdx.x] += u;
        __syncthreads();
    }
    int pos = tsum[threadIdx.x] - s0;
    for (int j = 0; j < 16; j++) {
        int i = threadIdx.x * 16 + j;
        if (f[i]) {
            rowidx[b * KSEL_ + pos] = b * S_ + i;
            rw[b * KSEL_ + pos] = expf(lg[i] - m) * inv;
            pos++;
        }
    }
}

// ---------------------------------------------------------------------------
// Aux loss: BCE-with-logits mean with flat-index union targets.
// ---------------------------------------------------------------------------
__global__ __launch_bounds__(256)
void loss_kernel(const float* __restrict__ logits, const int* __restrict__ flags,
                 float* __restrict__ partials) {
    __shared__ float red[256];
    int i = blockIdx.x * 256 + threadIdx.x;
    float l = logits[i];
    float t = 0.f;
    if (i < S_)
        t = (flags[i] | flags[S_ + i] | flags[2 * S_ + i] | flags[3 * S_ + i]) ? 1.f : 0.f;
    float v = fmaxf(l, 0.f) - l * t + log1pf(expf(-fabsf(l)));
    red[threadIdx.x] = v; __syncthreads();
    for (int s = 128; s; s >>= 1) {
        if (threadIdx.x < s) red[threadIdx.x] += red[threadIdx.x + s];
        __syncthreads();
    }
    if (threadIdx.x == 0) partials[blockIdx.x] = red[0];
}

__global__ void loss_final(const float* __restrict__ partials, float* __restrict__ out) {
    float v = partials[threadIdx.x];
#pragma unroll
    for (int s = 32; s; s >>= 1) v += __shfl_xor(v, s);
    if (threadIdx.x == 0) out[0] = v / (float)NTOK_;
}

// ---------------------------------------------------------------------------
// GEMM (round-7 measured best, bit-identical): fine-phased 128x256 pipeline,
// 3-slot LDS ring, counted vmcnt(6), persistent SUBS M-tiles per block.
// MODE 1: H = silu(gather(A) @ W1), bf16 (SUBS=4, grid 256 = 1 block/CU).
// MODE 2: out[rowidx[m]] = x[rowidx[m]] + (H@W2)[m]*rw[m] (SUBS=1).
// ---------------------------------------------------------------------------
template <int MODE, int N, int K, int SUBS>
__global__ __launch_bounds__(512, 2)
void gemm_pipe_kernel(const unsigned short* __restrict__ A,
                      const unsigned short* __restrict__ BT,
                      const int* __restrict__ rowidx,
                      const float* __restrict__ rw,
                      const float* __restrict__ x,
                      unsigned short* __restrict__ Hout,
                      float* __restrict__ Out) {
    constexpr int BM = 128, BN = 256, BK = 64;
    constexpr int KI = K / BK;
    constexpr int NT = N / BN;
    constexpr int MG = M_ / (BM * SUBS);
    constexpr int NWG = NT * MG;
    constexpr int CPX = NWG / 8;
    __shared__ __attribute__((aligned(16))) unsigned short As[3][BM * BK];
    __shared__ __attribute__((aligned(16))) unsigned short Bs[3][BN * BK];

    const int tid = threadIdx.x;
    const int w = tid >> 6, lane = tid & 63;
    const int wm = w >> 2, wn = w & 3;

    int wgid = blockIdx.y * NT + blockIdx.x;
    int swz = (wgid & 7) * CPX + (wgid >> 3);
    const int tile_n = (swz % NT) * BN;
    const int mgrp   = (swz / NT);

    const int srow = lane >> 3;
    const int sw = (lane & 7) ^ srow;
    const uint64_t abase = (uint64_t)(uintptr_t)A;
    const uint64_t bbase = (uint64_t)(uintptr_t)BT;
    uint64_t aaddr[SUBS][2], baddr[4];
#pragma unroll
    for (int s = 0; s < SUBS; ++s)
#pragma unroll
        for (int t = 0; t < 2; ++t) {
            int r = t * 64 + w * 8 + srow;
            int am = (mgrp * SUBS + s) * BM + r;
            int ar = (MODE == 1) ? rowidx[am] : am;
            aaddr[s][t] = abase + ((uint64_t)ar * K + (uint64_t)sw * 8) * 2ull;
        }
#pragma unroll
    for (int t = 0; t < 4; ++t) {
        int r = t * 64 + w * 8 + srow;
        baddr[t] = bbase + ((uint64_t)(tile_n + r) * K + (uint64_t)sw * 8) * 2ull;
    }

    auto gload = [&](unsigned short* lds, uint64_t gaddr) {
        __builtin_amdgcn_global_load_lds(
            (const __attribute__((address_space(1))) unsigned int*)(uintptr_t)gaddr,
            (__attribute__((address_space(3))) unsigned int*)lds, 16, 0, 0);
    };

    f32x4 acc[4][4];
#pragma unroll
    for (int i = 0; i < 4; i++)
#pragma unroll
        for (int j = 0; j < 4; j++) acc[i][j] = (f32x4){0.f, 0.f, 0.f, 0.f};

#pragma unroll
    for (int p = 0; p < 2; ++p) {
        const uint64_t koff = (uint64_t)p * (BK * 2);
        gload(&As[p][(0 * 64 + w * 8) * BK], aaddr[0][0] + koff);
        gload(&As[p][(1 * 64 + w * 8) * BK], aaddr[0][1] + koff);
#pragma unroll
        for (int t = 0; t < 4; ++t)
            gload(&Bs[p][(t * 64 + w * 8) * BK], baddr[t] + koff);
    }
    asm volatile("s_waitcnt vmcnt(6)" ::: "memory");
    asm volatile("s_barrier" ::: "memory");

    const int lr = lane & 15, quad = lane >> 4;
    int c = 0;
#pragma unroll
    for (int s = 0; s < SUBS; ++s) {
#pragma unroll 1
        for (int kt = 0; kt < KI; ++kt) {
            int pre = c + 2; if (pre >= 3) pre -= 3;
            const char* Abase_l = (const char*)&As[c][0];
            const char* Bbase_l = (const char*)&Bs[c][0];
            const bool cross = (kt + 2 >= KI);
            const bool do_stage = (s < SUBS - 1) || (kt + 2 < KI);
            const uint64_t sa0 = cross ? aaddr[(s + 1 < SUBS) ? s + 1 : s][0]
                                       : aaddr[s][0];
            const uint64_t sa1 = cross ? aaddr[(s + 1 < SUBS) ? s + 1 : s][1]
                                       : aaddr[s][1];
            const uint64_t koff = (uint64_t)((kt + 2) & (KI - 1)) * (BK * 2);

            // ================= phase 0 : ks = 0 =================
            {
                bf16x8 af[4], bfr[4];
                const int xo = (quad ^ (lr & 7)) * 16;
#pragma unroll
                for (int m4 = 0; m4 < 4; ++m4) {
                    int row = wm * 64 + m4 * 16 + lr;
                    af[m4] = *(const bf16x8*)(Abase_l + row * (BK * 2) + xo);
                }
#pragma unroll
                for (int n4 = 0; n4 < 4; ++n4) {
                    int col = wn * 64 + n4 * 16 + lr;
                    bfr[n4] = *(const bf16x8*)(Bbase_l + col * (BK * 2) + xo);
                }
                if (do_stage) {
                    gload(&As[pre][(0 * 64 + w * 8) * BK], sa0 + koff);
                    gload(&As[pre][(1 * 64 + w * 8) * BK], sa1 + koff);
                    gload(&Bs[pre][(w * 8) * BK], baddr[0] + koff);
                }
                asm volatile("s_barrier" ::: "memory");
                asm volatile("s_waitcnt lgkmcnt(0)" ::: "memory");
                __builtin_amdgcn_sched_barrier(0);
                __builtin_amdgcn_s_setprio(1);
#pragma unroll
                for (int m4 = 0; m4 < 4; ++m4)
#pragma unroll
                    for (int n4 = 0; n4 < 4; ++n4)
                        acc[m4][n4] = __builtin_amdgcn_mfma_f32_16x16x32_bf16(
                            af[m4], bfr[n4], acc[m4][n4], 0, 0, 0);
                __builtin_amdgcn_s_setprio(0);
                asm volatile("s_barrier" ::: "memory");
            }

            // ================= phase 1 : ks = 1 =================
            {
                bf16x8 af[4], bfr[4];
                const int xo = ((4 + quad) ^ (lr & 7)) * 16;
#pragma unroll
                for (int m4 = 0; m4 < 4; ++m4) {
                    int row = wm * 64 + m4 * 16 + lr;
                    af[m4] = *(const bf16x8*)(Abase_l + row * (BK * 2) + xo);
                }
#pragma unroll
                for (int n4 = 0; n4 < 4; ++n4) {
                    int col = wn * 64 + n4 * 16 + lr;
                    bfr[n4] = *(const bf16x8*)(Bbase_l + col * (BK * 2) + xo);
                }
                if (do_stage) {
#pragma unroll
                    for (int t = 1; t < 4; ++t)
                        gload(&Bs[pre][(t * 64 + w * 8) * BK], baddr[t] + koff);
                }
                asm volatile("s_barrier" ::: "memory");
                asm volatile("s_waitcnt lgkmcnt(0)" ::: "memory");
                __builtin_amdgcn_sched_barrier(0);
                __builtin_amdgcn_s_setprio(1);
#pragma unroll
                for (int m4 = 0; m4 < 4; ++m4)
#pragma unroll
                    for (int n4 = 0; n4 < 4; ++n4)
                        acc[m4][n4] = __builtin_amdgcn_mfma_f32_16x16x32_bf16(
                            af[m4], bfr[n4], acc[m4][n4], 0, 0, 0);
                __builtin_amdgcn_s_setprio(0);
                if (do_stage) {
                    asm volatile("s_waitcnt vmcnt(6)" ::: "memory");
                } else if (kt + 2 == KI) {
                    asm volatile("s_waitcnt vmcnt(0)" ::: "memory");
                }
                asm volatile("s_barrier" ::: "memory");
                c += 1; if (c >= 3) c = 0;
            }
        }

        if (MODE == 1) {
            const int tile_m = (mgrp * SUBS + s) * BM;
#pragma unroll
            for (int m4 = 0; m4 < 4; ++m4)
#pragma unroll
                for (int r = 0; r < 4; ++r) {
                    int m = tile_m + wm * 64 + m4 * 16 + quad * 4 + r;
#pragma unroll
                    for (int n4 = 0; n4 < 4; ++n4) {
                        int col = tile_n + wn * 64 + n4 * 16 + lr;
                        float v = acc[m4][n4][r];
                        v = v / (1.f + __expf(-v));
                        Hout[(uint64_t)m * N + col] = f2bf(v);
                    }
                }
            if (s + 1 < SUBS) {
#pragma unroll
                for (int i = 0; i < 4; i++)
#pragma unroll
                    for (int j = 0; j < 4; j++)
                        acc[i][j] = (f32x4){0.f, 0.f, 0.f, 0.f};
            }
        }
    }

    if (MODE == 2) {
        const int tile_m = mgrp * SUBS * BM;
#pragma unroll
        for (int m4 = 0; m4 < 4; ++m4)
#pragma unroll
            for (int r = 0; r < 4; ++r) {
                int m = tile_m + wm * 64 + m4 * 16 + quad * 4 + r;
                int grow = rowidx[m];
                float wgt = rw[m];
                uint64_t rb = (uint64_t)grow * D_;
#pragma unroll
                for (int n4 = 0; n4 < 4; ++n4) {
                    int col = tile_n + wn * 64 + n4 * 16 + lr;
                    Out[rb + col] = x[rb + col] + acc[m4][n4][r] * wgt;
                }
            }
    }
}

// ---------------------------------------------------------------------------
extern "C" void kernel_launch(void* const* d_in, const int* in_sizes, int n_in,
                              void* d_out, int out_size, void* d_ws, size_t ws_size,
                              hipStream_t stream) {
    const float* x  = (const float*)d_in[0];
    // d_in[1] = mask (unused: all-ones in setup, MLP ignores it)
    const float* Wr = (const float*)d_in[2];
    const float* W1 = (const float*)d_in[3];
    const float* W2 = (const float*)d_in[4];
    float* out = (float*)d_out;

    char* ws = (char*)d_ws;
    size_t off = 0;
    auto alloc = [&](size_t bytes) {
        char* p = ws + off;
        off = (off + bytes + 255) & ~(size_t)255;
        return p;
    };
    unsigned short* xb   = (unsigned short*)alloc((size_t)NTOK_ * D_ * 2);  // 33.5 MB
    unsigned short* W1bT = (unsigned short*)alloc((size_t)DFF_ * D_ * 2);   // 8.4 MB
    unsigned short* W2bT = (unsigned short*)alloc((size_t)D_ * DFF_ * 2);   // 8.4 MB
    unsigned short* H    = (unsigned short*)alloc((size_t)M_ * DFF_ * 2);   // 67 MB
    float* logits  = (float*)alloc(NTOK_ * 4);
    int*   rank    = (int*)alloc(NTOK_ * 4);
    int*   flags   = (int*)alloc(NTOK_ * 4);
    int*   rowidx  = (int*)alloc(M_ * 4);
    float* rwp     = (float*)alloc(M_ * 4);
    float* partials = (float*)alloc(64 * 4);

    (void)hipMemsetAsync(rank, 0, NTOK_ * 4, stream);

    // router (bid 0..4095) + W1/W2 transpose (bid 4096..12287) in one launch
    pre_kernel<<<NTOK_ / 4 + 2 * (DFF_ / 32) * (D_ / 32), 256, 0, stream>>>(
        x, Wr, logits, xb, out, W1, W1bT, W2, W2bT);
    rank_partial_kernel<<<512, 256, 0, stream>>>(logits, rank);
    compact_kernel<<<B_, 256, 0, stream>>>(logits, rank, flags, rowidx, rwp);
    loss_kernel<<<NTOK_ / 256, 256, 0, stream>>>(logits, flags, partials);
    loss_final<<<1, 64, 0, stream>>>(partials, out + (size_t)NTOK_ * D_);
    // GEMM1: H[8192][4096] = silu(gather(xb) @ W1)  -- persistent, 4 M-tiles/block
    gemm_pipe_kernel<1, DFF_, D_, 4><<<dim3(DFF_ / 256, M_ / (128 * 4)), 512, 0, stream>>>(
        xb, W1bT, rowidx, nullptr, nullptr, H, nullptr);
    // GEMM2: out[rowidx[m]] = x[rowidx[m]] + (H @ W2)[m] * rw[m]
    gemm_pipe_kernel<2, D_, DFF_, 1><<<dim3(D_ / 256, M_ / 128), 512, 0, stream>>>(
        H, W2bT, rowidx, rwp, x, nullptr, out);
}

// Round 17
// 346.864 us; speedup vs baseline: 1.3997x; 1.0227x over previous
//
#include <hip/hip_runtime.h>
#include <hip/hip_bf16.h>
#include <cstdint>

// Problem constants
#define B_ 4
#define S_ 4096
#define D_ 1024
#define DFF_ 4096
#define KSEL_ 2048
#define M_ (B_ * KSEL_)      // 8192 selected rows total
#define NTOK_ (B_ * S_)      // 16384

typedef short bf16x8 __attribute__((ext_vector_type(8)));
typedef float f32x4 __attribute__((ext_vector_type(4)));

__device__ inline unsigned short f2bf(float f) {
    union { float f; unsigned int u; } c; c.f = f;
    unsigned int u = c.u;
    unsigned int r = u + 0x7fffu + ((u >> 16) & 1u);
    return (unsigned short)(r >> 16);
}

// ---------------------------------------------------------------------------
// pre_kernel: router + W1/W2 transpose in ONE ordinary launch (blockIdx
// partition, disjoint work).  Blocks 0-63 additionally zero rank[] (replaces
// the hipMemsetAsync dispatch; rank_partial runs strictly after this kernel).
//   bid 0..4095      : router (4 waves x 1 row: logits, xb=bf16(x), out=x)
//   bid 4096..12287  : 8192 transpose tiles (W1 then W2), 256 thr = 32x8
// ---------------------------------------------------------------------------
__global__ __launch_bounds__(256)
void pre_kernel(const float* __restrict__ x, const float* __restrict__ Wr,
                float* __restrict__ logits, unsigned short* __restrict__ xb,
                float* __restrict__ out, int* __restrict__ rank,
                const float* __restrict__ W1, unsigned short* __restrict__ W1bT,
                const float* __restrict__ W2, unsigned short* __restrict__ W2bT) {
    if (blockIdx.x < NTOK_ / 4) {
        if (blockIdx.x < 64) rank[blockIdx.x * 256 + threadIdx.x] = 0;
        // ----- router (identical to measured round-16) -----
        int wid = threadIdx.x >> 6, lane = threadIdx.x & 63;
        int row = blockIdx.x * 4 + wid;
        const float* xr = x + (size_t)row * D_;
        unsigned short* xbr = xb + (size_t)row * D_;
        float* outr = out + (size_t)row * D_;
        float acc = 0.f;
#pragma unroll
        for (int j = 0; j < 4; j++) {
            int off = j * 256 + lane * 4;
            float4 v = *(const float4*)(xr + off);
            float4 w = *(const float4*)(Wr + off);
            acc += v.x * w.x + v.y * w.y + v.z * w.z + v.w * w.w;
            *(float4*)(outr + off) = v;
            ushort4 o;
            o.x = f2bf(v.x); o.y = f2bf(v.y); o.z = f2bf(v.z); o.w = f2bf(v.w);
            *(ushort4*)(xbr + off) = o;
        }
#pragma unroll
        for (int s = 32; s; s >>= 1) acc += __shfl_xor(acc, s);
        if (lane == 0) logits[row] = acc;
    } else {
        // ----- transpose (identical to measured round-16) -----
        __shared__ float tile[32][33];
        int id = blockIdx.x - NTOK_ / 4;
        const float* src; unsigned short* dst; int R, C, bx, by;
        if (id < (DFF_ / 32) * (D_ / 32)) {
            src = W1; dst = W1bT; R = D_; C = DFF_;
            bx = id % (DFF_ / 32); by = id / (DFF_ / 32);
        } else {
            id -= (DFF_ / 32) * (D_ / 32);
            src = W2; dst = W2bT; R = DFF_; C = D_;
            bx = id % (D_ / 32); by = id / (D_ / 32);
        }
        int tx = threadIdx.x & 31, ty = threadIdx.x >> 5;   // 32 x 8
        int c0 = bx * 32, r0 = by * 32;
        for (int i = ty; i < 32; i += 8)
            tile[i][tx] = src[(size_t)(r0 + i) * C + c0 + tx];
        __syncthreads();
        for (int i = ty; i < 32; i += 8)
            dst[(size_t)(c0 + i) * R + r0 + tx] = f2bf(tile[tx][i]);
    }
}

// ---------------------------------------------------------------------------
// Rank (split-j): partial rank over a 512-logit j-chunk, atomicAdd into rank[].
// ---------------------------------------------------------------------------
__global__ __launch_bounds__(256)
void rank_partial_kernel(const float* __restrict__ logits, int* __restrict__ rank) {
    __shared__ float lj[512];
    int b  = blockIdx.x >> 7;
    int ic = (blockIdx.x >> 3) & 15;
    int jc = blockIdx.x & 7;
    const float* L = logits + b * S_;
    for (int t = threadIdx.x; t < 512; t += 256) lj[t] = L[jc * 512 + t];
    __syncthreads();
    int i = ic * 256 + threadIdx.x;
    float li = L[i];
    int jbase = jc * 512;
    int r = 0;
    const float4* __restrict__ lj4 = (const float4*)lj;
#pragma unroll 4
    for (int q = 0; q < 128; q++) {
        float4 v = lj4[q];
        int jb = jbase + q * 4;
        r += (v.x > li) | ((v.x == li) & (jb     < i));
        r += (v.y > li) | ((v.y == li) & (jb + 1 < i));
        r += (v.z > li) | ((v.z == li) & (jb + 2 < i));
        r += (v.w > li) | ((v.w == li) & (jb + 3 < i));
    }
    atomicAdd(&rank[b * S_ + i], r);
}

// ---------------------------------------------------------------------------
// Compact (1024 threads, 4 elems/thread — logic verified in round-15 run):
// sel = rank < KSEL_; flags, softmax weights, prefix-sum -> rowidx/rw.
// ---------------------------------------------------------------------------
__global__ __launch_bounds__(1024)
void compact_kernel(const float* __restrict__ logits, const int* __restrict__ rank,
                    int* __restrict__ flags,
                    int* __restrict__ rowidx, float* __restrict__ rw) {
    __shared__ float lg[S_];
    __shared__ int f[S_];
    __shared__ int tsum[1024];
    __shared__ float red[1024];
    const int tid = threadIdx.x;
    int b = blockIdx.x;
    const float* L = logits + b * S_;
    const int* R = rank + b * S_;
    int* F = flags + b * S_;
    // load: 1024 float4s, one per thread
    {
        ((float4*)lg)[tid] = ((const float4*)L)[tid];
        int4 rk = ((const int4*)R)[tid];
        int4 fl;
        fl.x = rk.x < KSEL_; fl.y = rk.y < KSEL_;
        fl.z = rk.z < KSEL_; fl.w = rk.w < KSEL_;
        ((int4*)f)[tid] = fl;
        ((int4*)F)[tid] = fl;
    }
    __syncthreads();
    float mx = fmaxf(fmaxf(lg[tid * 4], lg[tid * 4 + 1]),
                     fmaxf(lg[tid * 4 + 2], lg[tid * 4 + 3]));
    red[tid] = mx; __syncthreads();
    for (int s = 512; s; s >>= 1) {
        if (tid < s) red[tid] = fmaxf(red[tid], red[tid + s]);
        __syncthreads();
    }
    float m = red[0];
    __syncthreads();

    float esum = 0.f;
    int s0 = 0;
#pragma unroll
    for (int j = 0; j < 4; j++) {
        int i = tid * 4 + j;
        s0 += f[i];
        if (f[i]) esum += expf(lg[i] - m);
    }
    red[tid] = esum; __syncthreads();
    for (int s = 512; s; s >>= 1) {
        if (tid < s) red[tid] += red[tid + s];
        __syncthreads();
    }
    float inv = 1.f / red[0];

    tsum[tid] = s0; __syncthreads();
    for (int s = 1; s < 1024; s <<= 1) {
        int u = (tid >= s) ? tsum[tid - s] : 0;
        __syncthreads();
        tsum[tid] += u;
        __syncthreads();
    }
    int pos = tsum[tid] - s0;
#pragma unroll
    for (int j = 0; j < 4; j++) {
        int i = tid * 4 + j;
        if (f[i]) {
            rowidx[b * KSEL_ + pos] = b * S_ + i;
            rw[b * KSEL_ + pos] = expf(lg[i] - m) * inv;
            pos++;
        }
    }
}

// ---------------------------------------------------------------------------
// Aux loss: BCE-with-logits mean with flat-index union targets.
// ---------------------------------------------------------------------------
__global__ __launch_bounds__(256)
void loss_kernel(const float* __restrict__ logits, const int* __restrict__ flags,
                 float* __restrict__ partials) {
    __shared__ float red[256];
    int i = blockIdx.x * 256 + threadIdx.x;
    float l = logits[i];
    float t = 0.f;
    if (i < S_)
        t = (flags[i] | flags[S_ + i] | flags[2 * S_ + i] | flags[3 * S_ + i]) ? 1.f : 0.f;
    float v = fmaxf(l, 0.f) - l * t + log1pf(expf(-fabsf(l)));
    red[threadIdx.x] = v; __syncthreads();
    for (int s = 128; s; s >>= 1) {
        if (threadIdx.x < s) red[threadIdx.x] += red[threadIdx.x + s];
        __syncthreads();
    }
    if (threadIdx.x == 0) partials[blockIdx.x] = red[0];
}

__global__ void loss_final(const float* __restrict__ partials, float* __restrict__ out) {
    float v = partials[threadIdx.x];
#pragma unroll
    for (int s = 32; s; s >>= 1) v += __shfl_xor(v, s);
    if (threadIdx.x == 0) out[0] = v / (float)NTOK_;
}

// ---------------------------------------------------------------------------
// GEMM (measured best, bit-identical): fine-phased 128x256 pipeline, 3-slot
// LDS ring, counted vmcnt(6), persistent SUBS M-tiles per block.
// MODE 1: H = silu(gather(A) @ W1), bf16 (SUBS=4, grid 256 = 1 block/CU).
// MODE 2: out[rowidx[m]] = x[rowidx[m]] + (H@W2)[m]*rw[m] (SUBS=1).
// ---------------------------------------------------------------------------
template <int MODE, int N, int K, int SUBS>
__global__ __launch_bounds__(512, 2)
void gemm_pipe_kernel(const unsigned short* __restrict__ A,
                      const unsigned short* __restrict__ BT,
                      const int* __restrict__ rowidx,
                      const float* __restrict__ rw,
                      const float* __restrict__ x,
                      unsigned short* __restrict__ Hout,
                      float* __restrict__ Out) {
    constexpr int BM = 128, BN = 256, BK = 64;
    constexpr int KI = K / BK;
    constexpr int NT = N / BN;
    constexpr int MG = M_ / (BM * SUBS);
    constexpr int NWG = NT * MG;
    constexpr int CPX = NWG / 8;
    __shared__ __attribute__((aligned(16))) unsigned short As[3][BM * BK];
    __shared__ __attribute__((aligned(16))) unsigned short Bs[3][BN * BK];

    const int tid = threadIdx.x;
    const int w = tid >> 6, lane = tid & 63;
    const int wm = w >> 2, wn = w & 3;

    int wgid = blockIdx.y * NT + blockIdx.x;
    int swz = (wgid & 7) * CPX + (wgid >> 3);
    const int tile_n = (swz % NT) * BN;
    const int mgrp   = (swz / NT);

    const int srow = lane >> 3;
    const int sw = (lane & 7) ^ srow;
    const uint64_t abase = (uint64_t)(uintptr_t)A;
    const uint64_t bbase = (uint64_t)(uintptr_t)BT;
    uint64_t aaddr[SUBS][2], baddr[4];
#pragma unroll
    for (int s = 0; s < SUBS; ++s)
#pragma unroll
        for (int t = 0; t < 2; ++t) {
            int r = t * 64 + w * 8 + srow;
            int am = (mgrp * SUBS + s) * BM + r;
            int ar = (MODE == 1) ? rowidx[am] : am;
            aaddr[s][t] = abase + ((uint64_t)ar * K + (uint64_t)sw * 8) * 2ull;
        }
#pragma unroll
    for (int t = 0; t < 4; ++t) {
        int r = t * 64 + w * 8 + srow;
        baddr[t] = bbase + ((uint64_t)(tile_n + r) * K + (uint64_t)sw * 8) * 2ull;
    }

    auto gload = [&](unsigned short* lds, uint64_t gaddr) {
        __builtin_amdgcn_global_load_lds(
            (const __attribute__((address_space(1))) unsigned int*)(uintptr_t)gaddr,
            (__attribute__((address_space(3))) unsigned int*)lds, 16, 0, 0);
    };

    f32x4 acc[4][4];
#pragma unroll
    for (int i = 0; i < 4; i++)
#pragma unroll
        for (int j = 0; j < 4; j++) acc[i][j] = (f32x4){0.f, 0.f, 0.f, 0.f};

#pragma unroll
    for (int p = 0; p < 2; ++p) {
        const uint64_t koff = (uint64_t)p * (BK * 2);
        gload(&As[p][(0 * 64 + w * 8) * BK], aaddr[0][0] + koff);
        gload(&As[p][(1 * 64 + w * 8) * BK], aaddr[0][1] + koff);
#pragma unroll
        for (int t = 0; t < 4; ++t)
            gload(&Bs[p][(t * 64 + w * 8) * BK], baddr[t] + koff);
    }
    asm volatile("s_waitcnt vmcnt(6)" ::: "memory");
    asm volatile("s_barrier" ::: "memory");

    const int lr = lane & 15, quad = lane >> 4;
    int c = 0;
#pragma unroll
    for (int s = 0; s < SUBS; ++s) {
#pragma unroll 1
        for (int kt = 0; kt < KI; ++kt) {
            int pre = c + 2; if (pre >= 3) pre -= 3;
            const char* Abase_l = (const char*)&As[c][0];
            const char* Bbase_l = (const char*)&Bs[c][0];
            const bool cross = (kt + 2 >= KI);
            const bool do_stage = (s < SUBS - 1) || (kt + 2 < KI);
            const uint64_t sa0 = cross ? aaddr[(s + 1 < SUBS) ? s + 1 : s][0]
                                       : aaddr[s][0];
            const uint64_t sa1 = cross ? aaddr[(s + 1 < SUBS) ? s + 1 : s][1]
                                       : aaddr[s][1];
            const uint64_t koff = (uint64_t)((kt + 2) & (KI - 1)) * (BK * 2);

            // ================= phase 0 : ks = 0 =================
            {
                bf16x8 af[4], bfr[4];
                const int xo = (quad ^ (lr & 7)) * 16;
#pragma unroll
                for (int m4 = 0; m4 < 4; ++m4) {
                    int row = wm * 64 + m4 * 16 + lr;
                    af[m4] = *(const bf16x8*)(Abase_l + row * (BK * 2) + xo);
                }
#pragma unroll
                for (int n4 = 0; n4 < 4; ++n4) {
                    int col = wn * 64 + n4 * 16 + lr;
                    bfr[n4] = *(const bf16x8*)(Bbase_l + col * (BK * 2) + xo);
                }
                if (do_stage) {
                    gload(&As[pre][(0 * 64 + w * 8) * BK], sa0 + koff);
                    gload(&As[pre][(1 * 64 + w * 8) * BK], sa1 + koff);
                    gload(&Bs[pre][(w * 8) * BK], baddr[0] + koff);
                }
                asm volatile("s_barrier" ::: "memory");
                asm volatile("s_waitcnt lgkmcnt(0)" ::: "memory");
                __builtin_amdgcn_sched_barrier(0);
                __builtin_amdgcn_s_setprio(1);
#pragma unroll
                for (int m4 = 0; m4 < 4; ++m4)
#pragma unroll
                    for (int n4 = 0; n4 < 4; ++n4)
                        acc[m4][n4] = __builtin_amdgcn_mfma_f32_16x16x32_bf16(
                            af[m4], bfr[n4], acc[m4][n4], 0, 0, 0);
                __builtin_amdgcn_s_setprio(0);
                asm volatile("s_barrier" ::: "memory");
            }

            // ================= phase 1 : ks = 1 =================
            {
                bf16x8 af[4], bfr[4];
                const int xo = ((4 + quad) ^ (lr & 7)) * 16;
#pragma unroll
                for (int m4 = 0; m4 < 4; ++m4) {
                    int row = wm * 64 + m4 * 16 + lr;
                    af[m4] = *(const bf16x8*)(Abase_l + row * (BK * 2) + xo);
                }
#pragma unroll
                for (int n4 = 0; n4 < 4; ++n4) {
                    int col = wn * 64 + n4 * 16 + lr;
                    bfr[n4] = *(const bf16x8*)(Bbase_l + col * (BK * 2) + xo);
                }
                if (do_stage) {
#pragma unroll
                    for (int t = 1; t < 4; ++t)
                        gload(&Bs[pre][(t * 64 + w * 8) * BK], baddr[t] + koff);
                }
                asm volatile("s_barrier" ::: "memory");
                asm volatile("s_waitcnt lgkmcnt(0)" ::: "memory");
                __builtin_amdgcn_sched_barrier(0);
                __builtin_amdgcn_s_setprio(1);
#pragma unroll
                for (int m4 = 0; m4 < 4; ++m4)
#pragma unroll
                    for (int n4 = 0; n4 < 4; ++n4)
                        acc[m4][n4] = __builtin_amdgcn_mfma_f32_16x16x32_bf16(
                            af[m4], bfr[n4], acc[m4][n4], 0, 0, 0);
                __builtin_amdgcn_s_setprio(0);
                if (do_stage) {
                    asm volatile("s_waitcnt vmcnt(6)" ::: "memory");
                } else if (kt + 2 == KI) {
                    asm volatile("s_waitcnt vmcnt(0)" ::: "memory");
                }
                asm volatile("s_barrier" ::: "memory");
                c += 1; if (c >= 3) c = 0;
            }
        }

        if (MODE == 1) {
            const int tile_m = (mgrp * SUBS + s) * BM;
#pragma unroll
            for (int m4 = 0; m4 < 4; ++m4)
#pragma unroll
                for (int r = 0; r < 4; ++r) {
                    int m = tile_m + wm * 64 + m4 * 16 + quad * 4 + r;
#pragma unroll
                    for (int n4 = 0; n4 < 4; ++n4) {
                        int col = tile_n + wn * 64 + n4 * 16 + lr;
                        float v = acc[m4][n4][r];
                        v = v / (1.f + __expf(-v));
                        Hout[(uint64_t)m * N + col] = f2bf(v);
                    }
                }
            if (s + 1 < SUBS) {
#pragma unroll
                for (int i = 0; i < 4; i++)
#pragma unroll
                    for (int j = 0; j < 4; j++)
                        acc[i][j] = (f32x4){0.f, 0.f, 0.f, 0.f};
            }
        }
    }

    if (MODE == 2) {
        const int tile_m = mgrp * SUBS * BM;
#pragma unroll
        for (int m4 = 0; m4 < 4; ++m4)
#pragma unroll
            for (int r = 0; r < 4; ++r) {
                int m = tile_m + wm * 64 + m4 * 16 + quad * 4 + r;
                int grow = rowidx[m];
                float wgt = rw[m];
                uint64_t rb = (uint64_t)grow * D_;
#pragma unroll
                for (int n4 = 0; n4 < 4; ++n4) {
                    int col = tile_n + wn * 64 + n4 * 16 + lr;
                    Out[rb + col] = x[rb + col] + acc[m4][n4][r] * wgt;
                }
            }
    }
}

// ---------------------------------------------------------------------------
extern "C" void kernel_launch(void* const* d_in, const int* in_sizes, int n_in,
                              void* d_out, int out_size, void* d_ws, size_t ws_size,
                              hipStream_t stream) {
    const float* x  = (const float*)d_in[0];
    // d_in[1] = mask (unused: all-ones in setup, MLP ignores it)
    const float* Wr = (const float*)d_in[2];
    const float* W1 = (const float*)d_in[3];
    const float* W2 = (const float*)d_in[4];
    float* out = (float*)d_out;

    char* ws = (char*)d_ws;
    size_t off = 0;
    auto alloc = [&](size_t bytes) {
        char* p = ws + off;
        off = (off + bytes + 255) & ~(size_t)255;
        return p;
    };
    unsigned short* xb   = (unsigned short*)alloc((size_t)NTOK_ * D_ * 2);  // 33.5 MB
    unsigned short* W1bT = (unsigned short*)alloc((size_t)DFF_ * D_ * 2);   // 8.4 MB
    unsigned short* W2bT = (unsigned short*)alloc((size_t)D_ * DFF_ * 2);   // 8.4 MB
    unsigned short* H    = (unsigned short*)alloc((size_t)M_ * DFF_ * 2);   // 67 MB
    float* logits  = (float*)alloc(NTOK_ * 4);
    int*   rank    = (int*)alloc(NTOK_ * 4);
    int*   flags   = (int*)alloc(NTOK_ * 4);
    int*   rowidx  = (int*)alloc(M_ * 4);
    float* rwp     = (float*)alloc(M_ * 4);
    float* partials = (float*)alloc(64 * 4);

    // router (bid 0..4095, also zeroes rank) + W1/W2 transpose (bid 4096..12287)
    pre_kernel<<<NTOK_ / 4 + 2 * (DFF_ / 32) * (D_ / 32), 256, 0, stream>>>(
        x, Wr, logits, xb, out, rank, W1, W1bT, W2, W2bT);
    rank_partial_kernel<<<512, 256, 0, stream>>>(logits, rank);
    compact_kernel<<<B_, 1024, 0, stream>>>(logits, rank, flags, rowidx, rwp);
    loss_kernel<<<NTOK_ / 256, 256, 0, stream>>>(logits, flags, partials);
    loss_final<<<1, 64, 0, stream>>>(partials, out + (size_t)NTOK_ * D_);
    // GEMM1: H[8192][4096] = silu(gather(xb) @ W1)  -- persistent, 4 M-tiles/block
    gemm_pipe_kernel<1, DFF_, D_, 4><<<dim3(DFF_ / 256, M_ / (128 * 4)), 512, 0, stream>>>(
        xb, W1bT, rowidx, nullptr, nullptr, H, nullptr);
    // GEMM2: out[rowidx[m]] = x[rowidx[m]] + (H @ W2)[m] * rw[m]
    gemm_pipe_kernel<2, D_, DFF_, 1><<<dim3(D_ / 256, M_ / 128), 512, 0, stream>>>(
        H, W2bT, rowidx, rwp, x, nullptr, out);
}